// Round 3
// baseline (93.482 us; speedup 1.0000x reference)
//
#include <hip/hip_runtime.h>

#define DD 256
#define HH 4
#define NW 4   // waves per block; one GRAPH per wave

#define WAVE_LDS_FENCE() asm volatile("s_waitcnt lgkmcnt(0)" ::: "memory")
#define WAVE_VM_FENCE()  asm volatile("s_waitcnt vmcnt(0)" ::: "memory")

// starts[g] = lower_bound(bi, g); starts[G] = N   (bi is sorted)
__global__ void starts_kernel(const int* __restrict__ bi, int* __restrict__ starts,
                              int N, int G) {
    int g = blockIdx.x * blockDim.x + threadIdx.x;
    if (g > G) return;
    int lo = 0, hi = N;
    while (lo < hi) { int mid = (lo + hi) >> 1; if (bi[mid] < g) lo = mid + 1; else hi = mid; }
    starts[g] = lo;
}

// One wave per graph.
// Score phase: QUAD per row (4 lanes/row, 16 rows/pass) -> coalesced 64B-line reads,
//              2 quad-shfl per head per pass, scores transposed through eb LDS.
// Pooling phase: lane = column block (coalesced, L2-hot re-read), weights via LDS broadcast.
__global__ __launch_bounds__(256) void fused_quad(
    const float* __restrict__ x, const int* __restrict__ starts,
    const float* __restrict__ W, const float* __restrict__ b,
    const float* __restrict__ temp, float* __restrict__ scores_ws,
    float* __restrict__ xp, float* __restrict__ aw, int N, int G) {

    __shared__ float4 Wl[256];       // W as [h][d4]: Wl[h*64 + d4]  (4 KB)
    __shared__ float4 eb[NW][64];    // per-wave score/weight transpose buffer (4 KB)

    const int t = threadIdx.x;
    Wl[t] = ((const float4*)W)[t];   // 256 threads x 1 float4 = full W
    __syncthreads();                 // only block-wide sync; waves independent after

    const int lane = t & 63;
    const int wid  = t >> 6;
    const int g = blockIdx.x * NW + wid;
    if (g >= G) return;

    const int s = starts[g];
    const int e = starts[g + 1];
    const int cnt = e - s;

    if (cnt == 0) {
        ((float4*)xp)[(size_t)g * 64 + lane] = make_float4(0.f, 0.f, 0.f, 0.f);
        return;
    }

    const float4* __restrict__ x4 = (const float4*)x;
    const float invT = 1.0f / temp[0];
    const float b0 = b[0], b1 = b[1], b2 = b[2], b3 = b[3];

    const int ngrp = (cnt + 63) >> 6;   // almost always 1 (mean cnt ~31)

    float m0 = -1e30f, m1 = -1e30f, m2 = -1e30f, m3 = -1e30f;
    float q0 = 0.f, q1 = 0.f, q2 = 0.f, q3 = 0.f;   // fast path: my row's scores
    bool v0 = false;

    if (ngrp == 1) {
        // ---- coalesced quad-per-row score pass ----
        const int rg = lane >> 2;        // row in 16-row group
        const int cg = lane & 3;         // quarter of the row (interleaved chunks)
        const int npass = (cnt + 15) >> 4;
        for (int p = 0; p < npass; ++p) {
            const int row = s + p * 16 + rg;
            const bool v = (row < e);
            const int rc = v ? row : (e - 1);
            const float4* __restrict__ xr = x4 + (size_t)rc * 64 + cg;
            float t0 = 0.f, t1 = 0.f, t2 = 0.f, t3 = 0.f;
            #pragma unroll 8
            for (int dd = 0; dd < 16; ++dd) {
                const float4 xv = xr[4 * dd];                 // quad covers 64B line
                const float4 w0 = Wl[      cg + 4 * dd];
                const float4 w1 = Wl[ 64 + cg + 4 * dd];
                const float4 w2 = Wl[128 + cg + 4 * dd];
                const float4 w3 = Wl[192 + cg + 4 * dd];
                t0 += xv.x*w0.x + xv.y*w0.y + xv.z*w0.z + xv.w*w0.w;
                t1 += xv.x*w1.x + xv.y*w1.y + xv.z*w1.z + xv.w*w1.w;
                t2 += xv.x*w2.x + xv.y*w2.y + xv.z*w2.z + xv.w*w2.w;
                t3 += xv.x*w3.x + xv.y*w3.y + xv.z*w3.z + xv.w*w3.w;
            }
            // reduce across the 4 lanes of the quad
            t0 += __shfl_xor(t0, 1); t0 += __shfl_xor(t0, 2);
            t1 += __shfl_xor(t1, 1); t1 += __shfl_xor(t1, 2);
            t2 += __shfl_xor(t2, 1); t2 += __shfl_xor(t2, 2);
            t3 += __shfl_xor(t3, 1); t3 += __shfl_xor(t3, 2);
            if (v && cg == 0)
                eb[wid][p * 16 + rg] = make_float4(t0, t1, t2, t3);
        }
        WAVE_LDS_FENCE();
        // transpose back: lane = row
        v0 = (lane < cnt);
        const float4 sv = eb[wid][lane];    // garbage for invalid lanes, masked below
        q0 = (sv.x + b0) * invT; q1 = (sv.y + b1) * invT;
        q2 = (sv.z + b2) * invT; q3 = (sv.w + b3) * invT;
        m0 = v0 ? q0 : -1e30f; m1 = v0 ? q1 : -1e30f;
        m2 = v0 ? q2 : -1e30f; m3 = v0 ? q3 : -1e30f;
    } else {
        // rare path: multiple 64-row groups; scores round-trip via workspace
        for (int grp = 0; grp < ngrp; ++grp) {
            const int r  = s + grp * 64 + lane;
            const bool v = (r < e);
            const int rc = v ? r : (e - 1);
            const float4* __restrict__ xr = x4 + (size_t)rc * 64;
            float t0 = 0.f, t1 = 0.f, t2 = 0.f, t3 = 0.f;
            #pragma unroll 4
            for (int d = 0; d < 64; ++d) {
                const float4 xv = xr[d];
                const float4 w0 = Wl[d], w1 = Wl[64 + d], w2 = Wl[128 + d], w3 = Wl[192 + d];
                t0 += xv.x*w0.x + xv.y*w0.y + xv.z*w0.z + xv.w*w0.w;
                t1 += xv.x*w1.x + xv.y*w1.y + xv.z*w1.z + xv.w*w1.w;
                t2 += xv.x*w2.x + xv.y*w2.y + xv.z*w2.z + xv.w*w2.w;
                t3 += xv.x*w3.x + xv.y*w3.y + xv.z*w3.z + xv.w*w3.w;
            }
            const float s0 = (t0 + b0) * invT, s1 = (t1 + b1) * invT;
            const float s2 = (t2 + b2) * invT, s3 = (t3 + b3) * invT;
            if (v) {
                ((float4*)scores_ws)[r] = make_float4(s0, s1, s2, s3);
                m0 = fmaxf(m0, s0); m1 = fmaxf(m1, s1);
                m2 = fmaxf(m2, s2); m3 = fmaxf(m3, s3);
            }
        }
    }

    // per-graph butterfly max (once per graph)
    #pragma unroll
    for (int off = 32; off; off >>= 1) {
        m0 = fmaxf(m0, __shfl_xor(m0, off));
        m1 = fmaxf(m1, __shfl_xor(m1, off));
        m2 = fmaxf(m2, __shfl_xor(m2, off));
        m3 = fmaxf(m3, __shfl_xor(m3, off));
    }

    float l0 = 0.f, l1 = 0.f, l2 = 0.f, l3 = 0.f;
    float4 ac0 = make_float4(0.f,0.f,0.f,0.f), ac1 = ac0, ac2 = ac0, ac3 = ac0;
    float e0 = 0.f, e1 = 0.f, e2 = 0.f, e3 = 0.f;   // fast-path unnormalized weights

    if (ngrp == 1) {
        if (v0) {
            e0 = __expf(q0 - m0); e1 = __expf(q1 - m1);
            e2 = __expf(q2 - m2); e3 = __expf(q3 - m3);
        }
        l0 = e0; l1 = e1; l2 = e2; l3 = e3;
        eb[wid][lane] = make_float4(e0, e1, e2, e3);
        WAVE_LDS_FENCE();
        // pooling: lane = column block; rows re-read coalesced (L1/L2-hot)
        #pragma unroll 4
        for (int i = 0; i < cnt; ++i) {
            const float4 xv = x4[(size_t)(s + i) * 64 + lane];
            const float4 ee = eb[wid][i];   // lane-uniform broadcast
            ac0.x += ee.x*xv.x; ac0.y += ee.x*xv.y; ac0.z += ee.x*xv.z; ac0.w += ee.x*xv.w;
            ac1.x += ee.y*xv.x; ac1.y += ee.y*xv.y; ac1.z += ee.y*xv.z; ac1.w += ee.y*xv.w;
            ac2.x += ee.z*xv.x; ac2.y += ee.z*xv.y; ac2.z += ee.z*xv.z; ac2.w += ee.z*xv.w;
            ac3.x += ee.w*xv.x; ac3.y += ee.w*xv.y; ac3.z += ee.w*xv.z; ac3.w += ee.w*xv.w;
        }
    } else {
        WAVE_VM_FENCE();   // our scores_ws stores visible before same-wave readback
        for (int grp = 0; grp < ngrp; ++grp) {
            const int base = s + grp * 64;
            const int r = base + lane;
            const bool v = (r < e);
            const int rc = v ? r : (e - 1);
            const float4 sv = ((const float4*)scores_ws)[rc];
            float f0 = 0.f, f1 = 0.f, f2 = 0.f, f3 = 0.f;
            if (v) {
                f0 = __expf(sv.x - m0); f1 = __expf(sv.y - m1);
                f2 = __expf(sv.z - m2); f3 = __expf(sv.w - m3);
            }
            l0 += f0; l1 += f1; l2 += f2; l3 += f3;
            WAVE_LDS_FENCE();                 // previous group's reads complete
            eb[wid][lane] = make_float4(f0, f1, f2, f3);
            WAVE_LDS_FENCE();
            const int cs = min(64, e - base);
            for (int i = 0; i < cs; ++i) {
                const float4 xv = x4[(size_t)(base + i) * 64 + lane];
                const float4 ee = eb[wid][i];
                ac0.x += ee.x*xv.x; ac0.y += ee.x*xv.y; ac0.z += ee.x*xv.z; ac0.w += ee.x*xv.w;
                ac1.x += ee.y*xv.x; ac1.y += ee.y*xv.y; ac1.z += ee.y*xv.z; ac1.w += ee.y*xv.w;
                ac2.x += ee.z*xv.x; ac2.y += ee.z*xv.y; ac2.z += ee.z*xv.z; ac2.w += ee.z*xv.w;
                ac3.x += ee.w*xv.x; ac3.y += ee.w*xv.y; ac3.z += ee.w*xv.z; ac3.w += ee.w*xv.w;
            }
        }
    }

    // per-graph butterfly sum
    #pragma unroll
    for (int off = 32; off; off >>= 1) {
        l0 += __shfl_xor(l0, off);
        l1 += __shfl_xor(l1, off);
        l2 += __shfl_xor(l2, off);
        l3 += __shfl_xor(l3, off);
    }

    const float il0 = 1.f/l0, il1 = 1.f/l1, il2 = 1.f/l2, il3 = 1.f/l3;
    float4 out;
    out.x = 0.25f*(ac0.x*il0 + ac1.x*il1 + ac2.x*il2 + ac3.x*il3);
    out.y = 0.25f*(ac0.y*il0 + ac1.y*il1 + ac2.y*il2 + ac3.y*il3);
    out.z = 0.25f*(ac0.z*il0 + ac1.z*il1 + ac2.z*il2 + ac3.z*il3);
    out.w = 0.25f*(ac0.w*il0 + ac1.w*il1 + ac2.w*il2 + ac3.w*il3);
    ((float4*)xp)[(size_t)g * 64 + lane] = out;

    // attention weights [H, N]: lane = row, coalesced within graph range
    if (ngrp == 1) {
        if (v0) {
            const int r = s + lane;
            aw[0 * (size_t)N + r] = e0 * il0;
            aw[1 * (size_t)N + r] = e1 * il1;
            aw[2 * (size_t)N + r] = e2 * il2;
            aw[3 * (size_t)N + r] = e3 * il3;
        }
    } else {
        for (int grp = 0; grp < ngrp; ++grp) {
            const int r = s + grp * 64 + lane;
            if (r < e) {
                const float4 sv = ((const float4*)scores_ws)[r];
                aw[0 * (size_t)N + r] = __expf(sv.x - m0) * il0;
                aw[1 * (size_t)N + r] = __expf(sv.y - m1) * il1;
                aw[2 * (size_t)N + r] = __expf(sv.z - m2) * il2;
                aw[3 * (size_t)N + r] = __expf(sv.w - m3) * il3;
            }
        }
    }
}

extern "C" void kernel_launch(void* const* d_in, const int* in_sizes, int n_in,
                              void* d_out, int out_size, void* d_ws, size_t ws_size,
                              hipStream_t stream) {
    const float* x    = (const float*)d_in[0];
    const int*   bi   = (const int*)d_in[1];
    // d_in[2] = num_graphs (derived from out_size)
    const float* W    = (const float*)d_in[3];
    const float* b    = (const float*)d_in[4];
    const float* temp = (const float*)d_in[5];

    const int N = in_sizes[0] / DD;
    const int G = (out_size - HH * N) / DD;

    float* xp = (float*)d_out;                    // [G, D]
    float* aw = (float*)d_out + (size_t)G * DD;   // [H, N]

    float* scores_ws = (float*)d_ws;                               // N*H floats
    int*   starts    = (int*)((char*)d_ws + (size_t)N * HH * 4);   // G+1 ints

    starts_kernel<<<(G + 1 + 255) / 256, 256, 0, stream>>>(bi, starts, N, G);
    fused_quad<<<(G + NW - 1) / NW, 256, 0, stream>>>(
        x, starts, W, b, temp, scores_ws, xp, aw, N, G);
}

// Round 4
// 87.633 us; speedup vs baseline: 1.0667x; 1.0667x over previous
//
#include <hip/hip_runtime.h>

#define DD 256
#define HH 4
#define NW 4   // waves per block; one GRAPH per wave (waves fully independent)

#define WAVE_LDS_FENCE() asm volatile("s_waitcnt lgkmcnt(0)" ::: "memory")
#define WAVE_VM_FENCE()  asm volatile("s_waitcnt vmcnt(0)" ::: "memory")

// starts[g] = lower_bound(bi, g); starts[G] = N   (bi is sorted)
__global__ void starts_kernel(const int* __restrict__ bi, int* __restrict__ starts,
                              int N, int G) {
    int g = blockIdx.x * blockDim.x + threadIdx.x;
    if (g > G) return;
    int lo = 0, hi = N;
    while (lo < hi) { int mid = (lo + hi) >> 1; if (bi[mid] < g) lo = mid + 1; else hi = mid; }
    starts[g] = lo;
}

// One wave per graph.
// Score phase: lane = row; W read via wave-UNIFORM global loads -> s_load (scalar K$),
//              keeping the LDS data pipe nearly idle (it was the round-2 bottleneck).
// Pooling phase: lane = column block (coalesced, L1/L2-hot), weights via eb LDS broadcast.
__global__ __launch_bounds__(256) void fused_sload(
    const float* __restrict__ x, const int* __restrict__ starts,
    const float* __restrict__ W, const float* __restrict__ b,
    const float* __restrict__ temp, float* __restrict__ scores_ws,
    float* __restrict__ xp, float* __restrict__ aw, int N, int G) {

    __shared__ float4 eb[NW][64];    // per-wave row-weight broadcast buffer (4 KB)

    const int t    = threadIdx.x;
    const int lane = t & 63;
    const int wid  = t >> 6;
    const int g = blockIdx.x * NW + wid;
    if (g >= G) return;

    const int s = starts[g];
    const int e = starts[g + 1];
    const int cnt = e - s;

    if (cnt == 0) {
        ((float4*)xp)[(size_t)g * 64 + lane] = make_float4(0.f, 0.f, 0.f, 0.f);
        return;
    }

    const float4* __restrict__ x4 = (const float4*)x;
    const float4* __restrict__ W4 = (const float4*)W;   // uniform-indexed -> SMEM
    const float invT = 1.0f / temp[0];
    const float b0 = b[0], b1 = b[1], b2 = b[2], b3 = b[3];

    const int ngrp = (cnt + 63) >> 6;   // almost always 1 (mean cnt ~31)

    float m0 = -1e30f, m1 = -1e30f, m2 = -1e30f, m3 = -1e30f;
    float q0 = 0.f, q1 = 0.f, q2 = 0.f, q3 = 0.f;   // fast path: my row's scores
    bool v0 = false;

    if (ngrp == 1) {
        const int r  = s + lane;
        v0 = (r < e);
        const int rc = v0 ? r : (e - 1);
        const float4* __restrict__ xr = x4 + (size_t)rc * 64;
        float t0 = 0.f, t1 = 0.f, t2 = 0.f, t3 = 0.f;
        #pragma unroll 8
        for (int d = 0; d < 64; ++d) {
            const float4 xv = xr[d];
            const float4 w0 = W4[d], w1 = W4[64 + d], w2 = W4[128 + d], w3 = W4[192 + d];
            t0 += xv.x*w0.x + xv.y*w0.y + xv.z*w0.z + xv.w*w0.w;
            t1 += xv.x*w1.x + xv.y*w1.y + xv.z*w1.z + xv.w*w1.w;
            t2 += xv.x*w2.x + xv.y*w2.y + xv.z*w2.z + xv.w*w2.w;
            t3 += xv.x*w3.x + xv.y*w3.y + xv.z*w3.z + xv.w*w3.w;
        }
        q0 = (t0 + b0) * invT; q1 = (t1 + b1) * invT;
        q2 = (t2 + b2) * invT; q3 = (t3 + b3) * invT;
        if (v0) { m0 = q0; m1 = q1; m2 = q2; m3 = q3; }
    } else {
        // rare path: multiple 64-row groups; scores round-trip via workspace
        for (int grp = 0; grp < ngrp; ++grp) {
            const int r  = s + grp * 64 + lane;
            const bool v = (r < e);
            const int rc = v ? r : (e - 1);
            const float4* __restrict__ xr = x4 + (size_t)rc * 64;
            float t0 = 0.f, t1 = 0.f, t2 = 0.f, t3 = 0.f;
            #pragma unroll 4
            for (int d = 0; d < 64; ++d) {
                const float4 xv = xr[d];
                const float4 w0 = W4[d], w1 = W4[64 + d], w2 = W4[128 + d], w3 = W4[192 + d];
                t0 += xv.x*w0.x + xv.y*w0.y + xv.z*w0.z + xv.w*w0.w;
                t1 += xv.x*w1.x + xv.y*w1.y + xv.z*w1.z + xv.w*w1.w;
                t2 += xv.x*w2.x + xv.y*w2.y + xv.z*w2.z + xv.w*w2.w;
                t3 += xv.x*w3.x + xv.y*w3.y + xv.z*w3.z + xv.w*w3.w;
            }
            const float s0 = (t0 + b0) * invT, s1 = (t1 + b1) * invT;
            const float s2 = (t2 + b2) * invT, s3 = (t3 + b3) * invT;
            if (v) {
                ((float4*)scores_ws)[r] = make_float4(s0, s1, s2, s3);
                m0 = fmaxf(m0, s0); m1 = fmaxf(m1, s1);
                m2 = fmaxf(m2, s2); m3 = fmaxf(m3, s3);
            }
        }
    }

    // per-graph butterfly max (once per graph)
    #pragma unroll
    for (int off = 32; off; off >>= 1) {
        m0 = fmaxf(m0, __shfl_xor(m0, off));
        m1 = fmaxf(m1, __shfl_xor(m1, off));
        m2 = fmaxf(m2, __shfl_xor(m2, off));
        m3 = fmaxf(m3, __shfl_xor(m3, off));
    }

    float l0 = 0.f, l1 = 0.f, l2 = 0.f, l3 = 0.f;
    float4 ac0 = make_float4(0.f,0.f,0.f,0.f), ac1 = ac0, ac2 = ac0, ac3 = ac0;
    float e0 = 0.f, e1 = 0.f, e2 = 0.f, e3 = 0.f;   // fast-path unnormalized weights

    if (ngrp == 1) {
        if (v0) {
            e0 = __expf(q0 - m0); e1 = __expf(q1 - m1);
            e2 = __expf(q2 - m2); e3 = __expf(q3 - m3);
        }
        l0 = e0; l1 = e1; l2 = e2; l3 = e3;
        eb[wid][lane] = make_float4(e0, e1, e2, e3);
        WAVE_LDS_FENCE();
        // pooling: lane = column block; rows re-read coalesced (L1/L2-hot)
        #pragma unroll 4
        for (int i = 0; i < cnt; ++i) {
            const float4 xv = x4[(size_t)(s + i) * 64 + lane];
            const float4 ee = eb[wid][i];   // lane-uniform broadcast
            ac0.x += ee.x*xv.x; ac0.y += ee.x*xv.y; ac0.z += ee.x*xv.z; ac0.w += ee.x*xv.w;
            ac1.x += ee.y*xv.x; ac1.y += ee.y*xv.y; ac1.z += ee.y*xv.z; ac1.w += ee.y*xv.w;
            ac2.x += ee.z*xv.x; ac2.y += ee.z*xv.y; ac2.z += ee.z*xv.z; ac2.w += ee.z*xv.w;
            ac3.x += ee.w*xv.x; ac3.y += ee.w*xv.y; ac3.z += ee.w*xv.z; ac3.w += ee.w*xv.w;
        }
    } else {
        WAVE_VM_FENCE();   // our scores_ws stores visible before same-wave readback
        for (int grp = 0; grp < ngrp; ++grp) {
            const int base = s + grp * 64;
            const int r = base + lane;
            const bool v = (r < e);
            const int rc = v ? r : (e - 1);
            const float4 sv = ((const float4*)scores_ws)[rc];
            float f0 = 0.f, f1 = 0.f, f2 = 0.f, f3 = 0.f;
            if (v) {
                f0 = __expf(sv.x - m0); f1 = __expf(sv.y - m1);
                f2 = __expf(sv.z - m2); f3 = __expf(sv.w - m3);
            }
            l0 += f0; l1 += f1; l2 += f2; l3 += f3;
            WAVE_LDS_FENCE();                 // previous group's reads complete
            eb[wid][lane] = make_float4(f0, f1, f2, f3);
            WAVE_LDS_FENCE();
            const int cs = min(64, e - base);
            for (int i = 0; i < cs; ++i) {
                const float4 xv = x4[(size_t)(base + i) * 64 + lane];
                const float4 ee = eb[wid][i];
                ac0.x += ee.x*xv.x; ac0.y += ee.x*xv.y; ac0.z += ee.x*xv.z; ac0.w += ee.x*xv.w;
                ac1.x += ee.y*xv.x; ac1.y += ee.y*xv.y; ac1.z += ee.y*xv.z; ac1.w += ee.y*xv.w;
                ac2.x += ee.z*xv.x; ac2.y += ee.z*xv.y; ac2.z += ee.z*xv.z; ac2.w += ee.z*xv.w;
                ac3.x += ee.w*xv.x; ac3.y += ee.w*xv.y; ac3.z += ee.w*xv.z; ac3.w += ee.w*xv.w;
            }
        }
    }

    // per-graph butterfly sum
    #pragma unroll
    for (int off = 32; off; off >>= 1) {
        l0 += __shfl_xor(l0, off);
        l1 += __shfl_xor(l1, off);
        l2 += __shfl_xor(l2, off);
        l3 += __shfl_xor(l3, off);
    }

    const float il0 = 1.f/l0, il1 = 1.f/l1, il2 = 1.f/l2, il3 = 1.f/l3;
    float4 out;
    out.x = 0.25f*(ac0.x*il0 + ac1.x*il1 + ac2.x*il2 + ac3.x*il3);
    out.y = 0.25f*(ac0.y*il0 + ac1.y*il1 + ac2.y*il2 + ac3.y*il3);
    out.z = 0.25f*(ac0.z*il0 + ac1.z*il1 + ac2.z*il2 + ac3.z*il3);
    out.w = 0.25f*(ac0.w*il0 + ac1.w*il1 + ac2.w*il2 + ac3.w*il3);
    ((float4*)xp)[(size_t)g * 64 + lane] = out;

    // attention weights [H, N]: lane = row, coalesced within graph range
    if (ngrp == 1) {
        if (v0) {
            const int r = s + lane;
            aw[0 * (size_t)N + r] = e0 * il0;
            aw[1 * (size_t)N + r] = e1 * il1;
            aw[2 * (size_t)N + r] = e2 * il2;
            aw[3 * (size_t)N + r] = e3 * il3;
        }
    } else {
        for (int grp = 0; grp < ngrp; ++grp) {
            const int r = s + grp * 64 + lane;
            if (r < e) {
                const float4 sv = ((const float4*)scores_ws)[r];
                aw[0 * (size_t)N + r] = __expf(sv.x - m0) * il0;
                aw[1 * (size_t)N + r] = __expf(sv.y - m1) * il1;
                aw[2 * (size_t)N + r] = __expf(sv.z - m2) * il2;
                aw[3 * (size_t)N + r] = __expf(sv.w - m3) * il3;
            }
        }
    }
}

extern "C" void kernel_launch(void* const* d_in, const int* in_sizes, int n_in,
                              void* d_out, int out_size, void* d_ws, size_t ws_size,
                              hipStream_t stream) {
    const float* x    = (const float*)d_in[0];
    const int*   bi   = (const int*)d_in[1];
    // d_in[2] = num_graphs (derived from out_size)
    const float* W    = (const float*)d_in[3];
    const float* b    = (const float*)d_in[4];
    const float* temp = (const float*)d_in[5];

    const int N = in_sizes[0] / DD;
    const int G = (out_size - HH * N) / DD;

    float* xp = (float*)d_out;                    // [G, D]
    float* aw = (float*)d_out + (size_t)G * DD;   // [H, N]

    float* scores_ws = (float*)d_ws;                               // N*H floats
    int*   starts    = (int*)((char*)d_ws + (size_t)N * HH * 4);   // G+1 ints

    starts_kernel<<<(G + 1 + 255) / 256, 256, 0, stream>>>(bi, starts, N, G);
    fused_sload<<<(G + NW - 1) / NW, 256, 0, stream>>>(
        x, starts, W, b, temp, scores_ws, xp, aw, N, G);
}